// Round 2
// baseline (697.113 us; speedup 1.0000x reference)
//
#include <hip/hip_runtime.h>

// NNGLS: y_decor, o_decor, o for N=200000, M=20, MLP 64->256->1.
//
// K1 (mlp_mfma_kernel): split-bf16 MFMA GEMM (x=xh+xl, w1=wh+wl; 3 passes
//     ah*bh + al*bh + ah*bl => ~fp32 accuracy). Wave owns 64 nodes (4 M-tiles
//     of mfma_f32_16x16x32_bf16); w1 staged frag-ordered in LDS (hi+lo, 64KB);
//     layer2 (relu->dot w2) fused via per-lane partials + shfl_xor reduction.
// K2 (solve_kernel): LANE-PAIR-SPLIT bordered 21x21 elimination.
//     Node i is handled by lanes (2u, 2u+1); lane h owns matrix columns of
//     parity h (packed upper storage: row r keeps slots s=r>>1..10 -> 131
//     regs/lane; h=0 has a harmless junk sub-diagonal slot on odd rows, h=1 a
//     junk duplicate-of-col-20 slot -- neither is ever read for real outputs).
//     Lane 0 carries the y border vector, lane 1 the o border vector.
//     Per step k: 1 shfl_xor broadcasts the pivot, ~11 shfl_xor exchange the
//     multiplier halves, then each lane rank-1-updates its own columns.
//     Peak live set ~230 regs/lane -> fits 256 (launch_bounds(64,2)) ->
//     2 waves/SIMD instead of 1, no AGPR/scratch spill, ~0.55x ops/lane.
//     FMA sequence per real entry is identical to the scalar version.

#define MM   20
#define PP   64
#define HH   256
#define EPSF 1e-12f

// packed pair-split storage: row r, slots s = (r>>1)..10, col c = 2s + h
#define QH(r)     ((r) >> 1)
#define AIDX(r)   (11*(r) - (QH(r)*(QH(r)-1) + ((r)&1)*QH(r)))
#define AT(r, s)  aL[AIDX(r) + (s) - QH(r)]

typedef __attribute__((ext_vector_type(8))) short bf16x8;
typedef __attribute__((ext_vector_type(4))) float f32x4;

static __device__ __forceinline__ unsigned short f2bf(float f) {
    unsigned int u = __builtin_bit_cast(unsigned int, f);
    u += 0x7fffu + ((u >> 16) & 1u);          // RNE
    return (unsigned short)(u >> 16);
}
static __device__ __forceinline__ float bf2f(unsigned short h) {
    unsigned int u = ((unsigned int)h) << 16;
    return __builtin_bit_cast(float, u);
}

__global__ __launch_bounds__(256, 2)
void mlp_mfma_kernel(const float* __restrict__ x,
                     const float* __restrict__ w1,
                     const float* __restrict__ b1,
                     const float* __restrict__ w2,
                     const float* __restrict__ b2,
                     float* __restrict__ o_out, int n)
{
    __shared__ __align__(16) short swh[PP * HH];   // 32 KB  w1 hi, frag order
    __shared__ __align__(16) short swl[PP * HH];   // 32 KB  w1 lo
    const int tid = threadIdx.x;

    // ---- stage w1 -> frag-ordered bf16 hi/lo ----
    {
        const int col = tid;                       // 256 cols, one per thread
        const int t = col >> 4, nn = col & 15;
        #pragma unroll
        for (int g = 0; g < 8; ++g) {              // k = g*8 + u
            const int s = g >> 2, q = g & 3;
            bf16x8 hv, lv;
            #pragma unroll
            for (int u = 0; u < 8; ++u) {
                float v = w1[(g * 8 + u) * HH + col];
                unsigned short h = f2bf(v);
                hv[u] = (short)h;
                lv[u] = (short)f2bf(v - bf2f(h));
            }
            const int base = ((((t * 2 + s) * 4 + q) * 16) + nn) * 8;
            *(bf16x8*)&swh[base] = hv;
            *(bf16x8*)&swl[base] = lv;
        }
    }
    __syncthreads();

    const int lane = tid & 63;
    const int wv   = tid >> 6;
    const int nn   = lane & 15;      // A-row (node) / B-col (hidden) / C-col
    const int q    = lane >> 4;      // quad
    const int wb   = blockIdx.x * 256 + wv * 64;   // first node of this wave

    float w2v[16], b1v[16];
    #pragma unroll
    for (int t = 0; t < 16; ++t) {
        w2v[t] = w2[t * 16 + nn];
        b1v[t] = b1[t * 16 + nn];
    }

    // ---- A fragments: 4 M-tiles x 2 k-steps, split hi/lo ----
    bf16x8 ah[4][2], al[4][2];
    #pragma unroll
    for (int mt = 0; mt < 4; ++mt) {
        const int row = wb + mt * 16 + nn;
        #pragma unroll
        for (int s = 0; s < 2; ++s) {
            float v[8];
            if (row < n) {
                const float* xp = x + (size_t)row * PP + s * 32 + q * 8;
                float4 va = *(const float4*)(xp);
                float4 vb = *(const float4*)(xp + 4);
                v[0]=va.x; v[1]=va.y; v[2]=va.z; v[3]=va.w;
                v[4]=vb.x; v[5]=vb.y; v[6]=vb.z; v[7]=vb.w;
            } else {
                #pragma unroll
                for (int u = 0; u < 8; ++u) v[u] = 0.0f;
            }
            bf16x8 h, l;
            #pragma unroll
            for (int u = 0; u < 8; ++u) {
                unsigned short hb = f2bf(v[u]);
                h[u] = (short)hb;
                l[u] = (short)f2bf(v[u] - bf2f(hb));
            }
            ah[mt][s] = h;
            al[mt][s] = l;
        }
    }

    float part[4][4];
    #pragma unroll
    for (int mt = 0; mt < 4; ++mt)
        #pragma unroll
        for (int r = 0; r < 4; ++r) part[mt][r] = 0.0f;

    #pragma unroll
    for (int t = 0; t < 16; ++t) {
        f32x4 acc[4];
        #pragma unroll
        for (int mt = 0; mt < 4; ++mt) acc[mt] = (f32x4)(0.0f);
        #pragma unroll
        for (int s = 0; s < 2; ++s) {
            const int fb = ((((t * 2 + s) * 4 + q) * 16) + nn) * 8;
            bf16x8 bh = *(const bf16x8*)&swh[fb];
            bf16x8 bl = *(const bf16x8*)&swl[fb];
            #pragma unroll
            for (int mt = 0; mt < 4; ++mt) {
                acc[mt] = __builtin_amdgcn_mfma_f32_16x16x32_bf16(ah[mt][s], bh, acc[mt], 0, 0, 0);
                acc[mt] = __builtin_amdgcn_mfma_f32_16x16x32_bf16(al[mt][s], bh, acc[mt], 0, 0, 0);
                acc[mt] = __builtin_amdgcn_mfma_f32_16x16x32_bf16(ah[mt][s], bl, acc[mt], 0, 0, 0);
            }
        }
        #pragma unroll
        for (int mt = 0; mt < 4; ++mt)
            #pragma unroll
            for (int r = 0; r < 4; ++r)
                part[mt][r] = fmaf(fmaxf(acc[mt][r] + b1v[t], 0.0f), w2v[t], part[mt][r]);
    }

    #pragma unroll
    for (int w = 1; w < 16; w <<= 1)
        #pragma unroll
        for (int mt = 0; mt < 4; ++mt)
            #pragma unroll
            for (int r = 0; r < 4; ++r)
                part[mt][r] += __shfl_xor(part[mt][r], w, 64);

    const float bb = b2[0];
    if (nn == 0) {
        #pragma unroll
        for (int mt = 0; mt < 4; ++mt) {
            const int row = wb + mt * 16 + q * 4;   // rows q*4+reg, reg=0..3
            if (row < n) {
                float4 o4 = make_float4(part[mt][0] + bb, part[mt][1] + bb,
                                        part[mt][2] + bb, part[mt][3] + bb);
                *(float4*)&o_out[row] = o4;
            }
        }
    }
}

__global__ __launch_bounds__(64, 2)
void solve_kernel(const float* __restrict__ pos,
                  const float* __restrict__ y,
                  const int*   __restrict__ nbr,
                  const float* __restrict__ theta,
                  const float* __restrict__ o_in,
                  float* __restrict__ yd,
                  float* __restrict__ od, int n)
{
    const int lane = threadIdx.x;          // 64 threads = 32 node pairs
    const int h_   = lane & 1;             // column-parity this lane owns
    const int i    = blockIdx.x * 32 + (lane >> 1);
    if (i >= n) return;

    const float sigma_sq = theta[0];
    const float phi      = theta[1];
    const float tau      = theta[2];
    const float tau_sq   = tau * sigma_sq;

    const float L2E = 1.44269504088896340736f;
    const float c1  = -phi * L2E;                       // exp(-phi*d) = exp2(c1*d)
    const float c0  = __builtin_amdgcn_logf(sigma_sq);  // log2(sigma^2)

    const float sqrtEPS = __builtin_amdgcn_sqrtf(EPSF);
    const float diagA   = __builtin_amdgcn_exp2f(fmaf(sqrtEPS, c1, c0)) + tau_sq;
    const float diagB   = sigma_sq + tau;               // border diagonal

    int idx[MM];
    const int4* nb4 = (const int4*)(nbr + (size_t)i * MM);
    #pragma unroll
    for (int k = 0; k < MM / 4; ++k) {
        int4 v = nb4[k];
        idx[4*k] = v.x; idx[4*k+1] = v.y; idx[4*k+2] = v.z; idx[4*k+3] = v.w;
    }

    float px[21], py[21];
    const float2* pos2 = (const float2*)pos;
    #pragma unroll
    for (int j = 0; j < MM; ++j) {
        float2 p = pos2[idx[j]];
        px[j] = p.x; py[j] = p.y;
    }
    {
        float2 p = pos2[i];
        px[20] = p.x; py[20] = p.y;
    }

    // coordinates of MY columns (c = 2s + h_, clamped to 20 at s=10)
    float pxc[11], pyc[11];
    #pragma unroll
    for (int s = 0; s < 10; ++s) {
        pxc[s] = h_ ? px[2*s+1] : px[2*s];
        pyc[s] = h_ ? py[2*s+1] : py[2*s];
    }
    pxc[10] = px[20];
    pyc[10] = py[20];

    // border vector: lane 0 carries y, lane 1 carries o
    float bv[21];
    {
        const float* src = h_ ? o_in : y;
        #pragma unroll
        for (int j = 0; j < MM; ++j) bv[j] = src[idx[j]];
        bv[20] = src[i];
    }

    // ---- build my half of the bordered covariance (packed, 131 regs) ----
    float aL[131];
    #pragma unroll
    for (int r = 0; r <= 20; ++r) {
        #pragma unroll
        for (int s = QH(r); s <= 10; ++s) {
            float dx = px[r] - pxc[s];
            float dy = py[r] - pyc[s];
            float d  = __builtin_amdgcn_sqrtf(fmaf(dx, dx, fmaf(dy, dy, EPSF)));
            float v  = __builtin_amdgcn_exp2f(fmaf(d, c1, c0));
            if (s == QH(r)) {
                // diagonal lives at the first slot of row r, on lane (r&1)
                const float dv = (r == 20) ? diagB : diagA;
                v = (h_ == (r & 1)) ? dv : v;
            }
            AT(r, s) = v;
        }
    }

    // ---- 20 elimination steps, pair-cooperative ----
    #pragma unroll
    for (int k = 0; k < 20; ++k) {
        // pivot broadcast (owner lane = k&1)
        float sendv = AT(k, QH(k));
        float recvv = __shfl_xor(sendv, 1, 64);
        float pd = ((k & 1) == h_) ? sendv : recvv;
        float rp = __builtin_amdgcn_rcpf(pd);
        rp = rp * (2.0f - pd * rp);                 // Newton refine

        // multipliers: my parity locally, partner parity via shfl_xor.
        // slot s holds m for row r = 2s + h_; partner slot holds r = 2s+1-h_.
        float ml[11], mo[11];
        #pragma unroll
        for (int s = QH(k); s <= 10; ++s) {
            float v = AT(k, s) * rp;
            if (s == QH(k))
                v = (2*s + h_ > k) ? v : 0.0f;      // mask pivot / junk subdiag
            ml[s] = v;
            mo[s] = __shfl_xor(v, 1, 64);
        }

        // rank-1 update of my columns, rows k+1..20
        #pragma unroll
        for (int r = k + 1; r <= 20; ++r) {
            float mr = ((r & 1) == h_) ? ml[QH(r)] : mo[QH(r)];
            bv[r] = fmaf(-mr, bv[k], bv[r]);
            #pragma unroll
            for (int s = QH(r); s <= 10; ++s)
                AT(r, s) = fmaf(-mr, AT(k, s), AT(r, s));
        }
    }

    // Schur complement f = a[20][20] lives on lane h=0
    float fs = AT(20, 10);
    float fo = __shfl_xor(fs, 1, 64);
    float f  = h_ ? fo : fs;
    float is = __builtin_amdgcn_rsqf(f);
    is = is * fmaf(-0.5f * f * is, is, 1.5f);

    float* dst = h_ ? od : yd;
    dst[i] = bv[20] * is;
}

extern "C" void kernel_launch(void* const* d_in, const int* in_sizes, int n_in,
                              void* d_out, int out_size, void* d_ws, size_t ws_size,
                              hipStream_t stream)
{
    const float* x     = (const float*)d_in[0];
    const float* pos   = (const float*)d_in[1];
    const float* y     = (const float*)d_in[2];
    const int*   nbr   = (const int*)  d_in[3];
    const float* theta = (const float*)d_in[4];
    const float* w1    = (const float*)d_in[5];
    const float* b1    = (const float*)d_in[6];
    const float* w2    = (const float*)d_in[7];
    const float* b2    = (const float*)d_in[8];

    const int n = in_sizes[2];                 // N
    float* out = (float*)d_out;
    float* yd = out;
    float* od = out + (size_t)n;
    float* oo = out + 2 * (size_t)n;

    mlp_mfma_kernel<<<(n + 255) / 256, 256, 0, stream>>>(x, w1, b1, w2, b2, oo, n);
    solve_kernel<<<(n + 31) / 32, 64, 0, stream>>>(pos, y, nbr, theta, oo, yd, od, n);
}